// Round 1
// baseline (4997.271 us; speedup 1.0000x reference)
//
#include <hip/hip_runtime.h>
#include <cstdint>
#include <cstddef>

// Problem constants
#define TT   64
#define BB   32
#define CINC 64
#define HIDN 128
#define LL   256
#define LPP  128
#define NSAMP (TT*BB)   // 2048
#define LN_EPS 1e-5f

// ---------- small helpers ----------
__device__ __forceinline__ float bf2f(unsigned short u){
    union { unsigned int i; float f; } v; v.i = ((unsigned int)u) << 16; return v.f;
}
__device__ __forceinline__ unsigned short f2bf(float f){
    union { float f; unsigned int i; } v; v.f = f;
    unsigned int u = v.i;
    u = (u + 0x7FFFu + ((u >> 16) & 1u)) >> 16;   // RTNE
    return (unsigned short)u;
}
__device__ __forceinline__ float sigmoidf_(float x){ return 1.f/(1.f + __expf(-x)); }
__device__ __forceinline__ float tanhf_(float x){ return 1.f - 2.f/(__expf(2.f*x) + 1.f); }

// =====================================================================
// Phase 1: conv1d(x) + LN + maxpool -> bf16 xg.
// Round-2 change: 512 threads/block (8 waves, 16 rows per wave) instead of
// 256/4x32. Halves per-thread accumulator state (64 VGPR acc) so
// __launch_bounds__(512,2) gives 4 waves/SIMD (was 2) to hide the per-c
// global/scalar load latency. Same total FMA work.
// =====================================================================
__global__ __launch_bounds__(512, 2) void phase1_kernel(
    const float* __restrict__ x,
    const float* __restrict__ wx0, const float* __restrict__ bx0,
    const float* __restrict__ wx1, const float* __restrict__ bx1,
    const float* __restrict__ wx2, const float* __restrict__ bx2,
    const float* __restrict__ wx3, const float* __restrict__ bx3,
    const float* __restrict__ lnw, const float* __restrict__ lnb,
    unsigned int* __restrict__ xg)     // [4][NSAMP][HID][LP/2] dwords (2x bf16)
{
    const int s = blockIdx.x;          // sample (t*B+b)
    const int g = blockIdx.y;          // gate

    const float* W; const float* Bv;
    if (g == 0)      { W = wx0; Bv = bx0; }
    else if (g == 1) { W = wx1; Bv = bx1; }
    else if (g == 2) { W = wx2; Bv = bx2; }
    else             { W = wx3; Bv = bx3; }

    const int tid  = threadIdx.x;
    const int lane = tid & 63;
    const int wv    = __builtin_amdgcn_readfirstlane(tid >> 6);  // 0..7
    const int obase = wv * 16;

    const float* xs = x + (size_t)s * (CINC * LL);
    const int l0 = lane * 4;

    float acc[16][4];
    #pragma unroll
    for (int r = 0; r < 16; r++){ acc[r][0]=0.f; acc[r][1]=0.f; acc[r][2]=0.f; acc[r][3]=0.f; }

    for (int c = 0; c < CINC; c++){
        const float* xr = xs + c * LL;
        float xv[6];
        #pragma unroll
        for (int d = 0; d < 6; d++){
            int l = l0 + d - 1;
            xv[d] = (l >= 0 && l < LL) ? xr[l] : 0.f;
        }
        const float* wc = W + (size_t)c * 3;
        #pragma unroll
        for (int r = 0; r < 16; r++){
            const int o = obase + r;
            const float* wo = wc + (size_t)o * (CINC * 3);
            const float w0 = wo[0], w1 = wo[1], w2 = wo[2];
            #pragma unroll
            for (int q = 0; q < 4; q++){
                acc[r][q] += w0 * xv[q] + w1 * xv[q+1] + w2 * xv[q+2];
            }
        }
    }

    float sum = 0.f, ssq = 0.f;
    #pragma unroll
    for (int r = 0; r < 16; r++){
        const float bo = Bv[obase + r];
        #pragma unroll
        for (int q = 0; q < 4; q++){
            float v = acc[r][q] + bo;
            acc[r][q] = v;
            sum += v; ssq += v * v;
        }
    }

    #pragma unroll
    for (int off = 32; off > 0; off >>= 1){
        sum += __shfl_down(sum, off, 64);
        ssq += __shfl_down(ssq, off, 64);
    }
    __shared__ float red[16];
    if (lane == 0){ red[wv] = sum; red[8 + wv] = ssq; }
    __syncthreads();
    float ts = 0.f, tq = 0.f;
    #pragma unroll
    for (int w = 0; w < 8; w++){ ts += red[w]; tq += red[8 + w]; }
    const float mu  = ts * (1.f / 32768.f);
    const float var = tq * (1.f / 32768.f) - mu * mu;
    const float inv = rsqrtf(var + LN_EPS);

    unsigned int* outb = xg + ((size_t)g * NSAMP + s) * (HIDN * (LPP/2));
    #pragma unroll
    for (int r = 0; r < 16; r++){
        const int o = obase + r;
        const float4 lw = *(const float4*)(lnw + (size_t)o * LL + l0);
        const float4 lb = *(const float4*)(lnb + (size_t)o * LL + l0);
        const float v0 = (acc[r][0] - mu) * inv * lw.x + lb.x;
        const float v1 = (acc[r][1] - mu) * inv * lw.y + lb.y;
        const float v2 = (acc[r][2] - mu) * inv * lw.z + lb.z;
        const float v3 = (acc[r][3] - mu) * inv * lw.w + lb.w;
        const float p0 = fmaxf(v0, v1);
        const float p1 = fmaxf(v2, v3);
        const unsigned int pk = (unsigned int)f2bf(p0) | ((unsigned int)f2bf(p1) << 16);
        outb[(size_t)o * (LPP/2) + lane] = pk;
    }
}

// =====================================================================
// Phase 2: weights staged to LDS once per block per step, transposed to
// [c3k][slot][hid4] with slot swizzle so the hot loop reads wave-uniform
// ds_read_b128 (broadcast, conflict-free) and does pure VGPR v_fma_f32.
// Round-2 change: explicit software prefetch of the next-c h row so the
// L2-hit latency (~200 cyc) of hprev overlaps the current c's 48 FMAs.
// Block = 128 threads (thread = l), grid = (B=32, hq=32). Lane owns
// (4 gates x 4 hid) at its l.
// =====================================================================
__global__ __launch_bounds__(128) void phase2_kernel(
    const float* __restrict__ hprev,          // [B][HID][LP]
    const unsigned short* __restrict__ xg,    // [4][NSAMP][HID][LP] bf16
    const float* __restrict__ wh0, const float* __restrict__ bh0,
    const float* __restrict__ wh1, const float* __restrict__ bh1,
    const float* __restrict__ wh2, const float* __restrict__ bh2,
    const float* __restrict__ wh3, const float* __restrict__ bh3,
    float* __restrict__ hout,                 // d_out + t*B*HID*LP
    float* __restrict__ cst,                  // [B][HID][LP]
    int t, int first)
{
    const int b   = blockIdx.x;
    const int hq  = blockIdx.y;      // 4 hid channels per block
    const int tid = threadIdx.x;     // = l, 0..127
    const int l   = tid;

    // LDS: [384 c3k][4 slot][4 h] floats = 24 KB. slot = (g + (c3k>>2)) & 3.
    __shared__ float wlds[384 * 16];

    float acc[4][4];
    #pragma unroll
    for (int g = 0; g < 4; g++)
        #pragma unroll
        for (int h = 0; h < 4; h++) acc[g][h] = 0.f;

    if (!first){
        // ---- stage weights: 16 rows (g,h) x 384 floats, coalesced float4
        // global reads, transposed scalar LDS writes (swizzled slot). ----
        // j in [0,1536): r = j/96 (row = g*4+h), p = j%96 (float4 within row)
        #pragma unroll
        for (int it = 0; it < 12; ++it){
            const int j = tid + 128 * it;
            const int r = j / 96;
            const int p = j - r * 96;
            const int g = r >> 2, h = r & 3;
            const float* Wg = (g == 0) ? wh0 : (g == 1) ? wh1 : (g == 2) ? wh2 : wh3;
            const float4 v = *(const float4*)(Wg + ((size_t)(hq * 4 + h)) * 384 + p * 4);
            const int s = (g + p) & 3;              // swizzle key = (c3k>>2)&3 == p&3
            const int base = (p * 4) * 16 + s * 4 + h;
            wlds[base]      = v.x;   // c3k = 4p+0
            wlds[base + 16] = v.y;   // c3k = 4p+1
            wlds[base + 32] = v.z;   // c3k = 4p+2
            wlds[base + 48] = v.w;   // c3k = 4p+3
        }
        __syncthreads();

        const float* hb = hprev + (size_t)b * (HIDN * LPP);
        const float4* wlds4 = (const float4*)wlds;

        // prefetch c = 0
        float nv0 = (l > 0)       ? hb[l - 1] : 0.f;
        float nv1 =                 hb[l];
        float nv2 = (l < LPP - 1) ? hb[l + 1] : 0.f;

        #pragma unroll 2
        for (int c = 0; c < HIDN; c++){
            const float hv0 = nv0;
            const float hv1 = nv1;
            const float hv2 = nv2;
            // issue next row's loads before this row's FMAs (latency overlap)
            const int cn = (c + 1 < HIDN) ? (c + 1) : c;
            const float* hr = hb + cn * LPP;
            nv0 = (l > 0)       ? hr[l - 1] : 0.f;
            nv1 =                 hr[l];
            nv2 = (l < LPP - 1) ? hr[l + 1] : 0.f;

            #pragma unroll
            for (int k = 0; k < 3; k++){
                const float hk = (k == 0) ? hv0 : (k == 1) ? hv1 : hv2;
                const int c3k = c * 3 + k;
                #pragma unroll
                for (int g = 0; g < 4; g++){
                    const int s = (g + ((c3k >> 2) & 3)) & 3;
                    const float4 w = wlds4[c3k * 4 + s];
                    acc[g][0] += w.x * hk;
                    acc[g][1] += w.y * hk;
                    acc[g][2] += w.z * hk;
                    acc[g][3] += w.w * hk;
                }
            }
        }
    }

    const float* bhp[4] = { bh0, bh1, bh2, bh3 };
    const int sidx = t * BB + b;
    float pre[4][4];
    #pragma unroll
    for (int g = 0; g < 4; g++){
        #pragma unroll
        for (int h = 0; h < 4; h++){
            const int hid = hq * 4 + h;
            const float xgv = bf2f(xg[(((size_t)g * NSAMP + sidx) * HIDN + hid) * LPP + l]);
            pre[g][h] = acc[g][h] + bhp[g][hid] + xgv;
        }
    }

    #pragma unroll
    for (int h = 0; h < 4; h++){
        const int hid = hq * 4 + h;
        float* cp = cst + ((size_t)b * HIDN + hid) * LPP + l;
        const float cv = first ? 0.f : *cp;
        const float ig = sigmoidf_(pre[0][h]);
        const float fg = sigmoidf_(pre[1][h]);
        const float gg = tanhf_(pre[2][h]);
        const float og = sigmoidf_(pre[3][h]);
        const float cn = fg * cv + ig * gg;
        *cp = cn;
        hout[((size_t)b * HIDN + hid) * LPP + l] = og * tanhf_(cn);
    }
}

// =====================================================================
// Host side
// =====================================================================
extern "C" void kernel_launch(void* const* d_in, const int* in_sizes, int n_in,
                              void* d_out, int out_size, void* d_ws, size_t ws_size,
                              hipStream_t stream)
{
    const float* x = (const float*)d_in[0];

    const float* wxp[4] = {nullptr,nullptr,nullptr,nullptr};
    const float* bxp[4] = {nullptr,nullptr,nullptr,nullptr};
    const float* whp[4] = {nullptr,nullptr,nullptr,nullptr};
    const float* bhp[4] = {nullptr,nullptr,nullptr,nullptr};
    const float* lnw = nullptr; const float* lnb = nullptr;
    int nwx = 0, nwh = 0, pend = -1;
    for (int i = 1; i < n_in; i++){
        const float* p = (const float*)d_in[i];
        const int sz = in_sizes[i];
        if (sz == HIDN * CINC * 3)      { wxp[nwx] = p; pend = 0; }
        else if (sz == HIDN * HIDN * 3) { whp[nwh] = p; pend = 1; }
        else if (sz == HIDN)            { if (pend == 0) bxp[nwx++] = p; else bhp[nwh++] = p; pend = -1; }
        else if (sz == HIDN * LL)       { if (!lnw) lnw = p; else lnb = p; }
    }

    // Workspace: xg (bf16, 256 MiB) then c-state (fp32, 2 MiB).
    unsigned int*   xg_u32 = (unsigned int*)d_ws;
    unsigned short* xg_u16 = (unsigned short*)d_ws;
    const size_t xg_bytes = (size_t)4 * NSAMP * HIDN * LPP * 2;
    float* cst = (float*)((char*)d_ws + xg_bytes);
    float* out = (float*)d_out;

    phase1_kernel<<<dim3(NSAMP, 4), 512, 0, stream>>>(
        x, wxp[0], bxp[0], wxp[1], bxp[1], wxp[2], bxp[2], wxp[3], bxp[3],
        lnw, lnb, xg_u32);

    for (int t = 0; t < TT; t++){
        const float* hprev = (t == 0) ? out : out + (size_t)(t - 1) * BB * HIDN * LPP;
        phase2_kernel<<<dim3(BB, 32), 128, 0, stream>>>(
            hprev, xg_u16,
            whp[0], bhp[0], whp[1], bhp[1], whp[2], bhp[2], whp[3], bhp[3],
            out + (size_t)t * BB * HIDN * LPP, cst, t, (t == 0) ? 1 : 0);
    }
}